// Round 5
// baseline (400.841 us; speedup 1.0000x reference)
//
#include <hip/hip_runtime.h>
#include <hip/hip_bf16.h>
#include <cstdint>

// ---------------- problem dims ----------------
#define BS 8
#define SEQ 2048
#define HDIM 1024
#define NH 16
#define HD 64
#define M_ROWS (BS * SEQ)   // 16384
#define N_COLS (2 * HDIM)   // 2048 GEMM cols: 0..1023 = K1 (dots only), 1024..2047 = V1
#define KDIM HDIM           // 1024

#define DELTA 0.025f
#define FLAG_CAP 32768           // flat flagged-task list; expected ~6200 total

// ---------------- workspace layout (bytes) ----------------
#define OFF_A      ((size_t)0)           // bf16 A [M,K]             33,554,432
#define OFF_BT     ((size_t)33554432)    // bf16 Bt [N,K]             4,194,304
#define OFF_FCNT   ((size_t)37748736)    // int
#define OFF_FLIST  ((size_t)37748800)    // int[FLAG_CAP]               131,072
#define OFF_BIAS   ((size_t)37879872)    // f32 [2048]
#define OFF_CVH    ((size_t)41943040)    // bf16 CV [B][NH][SEQ][HD]  33,554,432
#define OFF_VALID  ((size_t)75497472)    // u8 [BS][NH][SEQ]             262,144
#define OFF_MAPS   ((size_t)75759616)    // ushort4 [BS][SEQ][NH]      2,097,152
// total ~78 MB

typedef __attribute__((ext_vector_type(8))) __bf16 bf16x8;
typedef __attribute__((ext_vector_type(4))) float f32x4;

// float -> bf16 bits, round-to-nearest-even (inputs are finite)
__device__ __forceinline__ unsigned short f2bf(float f) {
    unsigned int x = __builtin_bit_cast(unsigned int, f);
    unsigned int r = x + 0x7fffu + ((x >> 16) & 1u);
    return (unsigned short)(r >> 16);
}
__device__ __forceinline__ float bf2f(unsigned short u) {
    return __builtin_bit_cast(float, (unsigned int)u << 16);
}

// async 16B global -> LDS (dest = wave-uniform LDS base + lane*16)
__device__ __forceinline__ void g2l16(const void* gp, void* lp) {
    __builtin_amdgcn_global_load_lds(
        (__attribute__((address_space(1))) void*)(void*)gp,
        (__attribute__((address_space(3))) void*)lp, 16, 0, 0);
}

// ---------------- fused prep: hs->bf16 | W transpose->bf16 | bias+fcnt ----------------
__global__ __launch_bounds__(256) void prep_kernel(const float4* __restrict__ hs4,
                                                   ushort4* __restrict__ Abf4,
                                                   const float* __restrict__ K1w,
                                                   const float* __restrict__ V1w,
                                                   unsigned short* __restrict__ Bt,
                                                   const float* __restrict__ K1b,
                                                   const float* __restrict__ V1b,
                                                   float* __restrict__ bias,
                                                   int* __restrict__ fcnt) {
    __shared__ float tile[32][33];
    const int blk = blockIdx.x;
    const int t = threadIdx.x;
    if (blk < 16384) {
        int i = blk * 256 + t;            // 4,194,304 float4s
        float4 v = hs4[i];
        ushort4 o;
        o.x = f2bf(v.x); o.y = f2bf(v.y); o.z = f2bf(v.z); o.w = f2bf(v.w);
        Abf4[i] = o;
    } else if (blk < 18432) {
        int lb = blk - 16384;             // 0..2047 = tn + 32*tk + 1024*z
        int z = lb >> 10;
        int tk = (lb >> 5) & 31;
        int tn = lb & 31;
        const float* W = z ? V1w : K1w;
        int r = t >> 3;                   // 0..31
        int c4 = (t & 7) * 4;             // 0,4,..,28
        const float4 v = *(const float4*)&W[(size_t)(tk * 32 + r) * 1024 + tn * 32 + c4];
        tile[r][c4 + 0] = v.x; tile[r][c4 + 1] = v.y;
        tile[r][c4 + 2] = v.z; tile[r][c4 + 3] = v.w;
        __syncthreads();
        int n = tn * 32 + r;
        int k = tk * 32 + c4;
        ushort4 o;
        o.x = f2bf(tile[c4 + 0][r]); o.y = f2bf(tile[c4 + 1][r]);
        o.z = f2bf(tile[c4 + 2][r]); o.w = f2bf(tile[c4 + 3][r]);
        *(ushort4*)&Bt[((size_t)z * 1024 + n) * 1024 + k] = o;
    } else {
        int i = (blk - 18432) * 256 + t;  // 0..2047
        bias[i] = (i < 1024) ? K1b[i] : V1b[i - 1024];
        if (i == 0) *fcnt = 0;
    }
}

// ---------------- GEMM + fused dots ----------------
// 256x256 tile, BK=64, 8 waves (2M x 4N), per-wave 128x64 output, acc[8][4].
// 4-phase K-tile schedule, counted vmcnt, RACE-FIXED tile-start sync:
//   per tile: stage B(t+1); s_waitcnt vmcnt(4); s_barrier (+compiler fences)
//             <- vmcnt is PER-WAVE and each wave's DMA writes only its own
//                1KB segments, so cross-wave residency needs vmcnt THEN
//                barrier BEFORE any ds_read of the tile (round-3 bug: phase
//                ds_reads preceded any barrier postdating the vmcnt).
//   then ph1 (mh0,kk0); stage A(t+1); ph2 (mh0,kk4); ph3 (mh1,kk0); ph4 (mh1,kk4)
// Each phase: sched_barrier pin -> 8 ds_read_b128 -> s_barrier -> setprio(1)
// 16 MFMA setprio(0) -> s_barrier. vmcnt never drains below 4 in the loop;
// every chunk gets >=3 phases of landing slack (A(t) staged mid-tile t-1).
// WAR safety: stages into buf X issue only after the barrier closing X's
// last reads. Trailing vmcnt(0) before epilogue (no DMA after LDS dealloc).
// XOR-swizzled staging (physical 16B-group g of row r holds logical g^(r&7));
// XCD-aware bijective swizzle (512 wgs % 8 == 0).
// n0 <  1024: fused dots epilogue (valid + flag list), K-half never stored.
// n0 >= 1024: relu(acc+bias) -> CVh bf16, HEAD-MAJOR layout [b][head][l][hd].
__global__ __launch_bounds__(512, 2) void gemm_kernel(const unsigned short* __restrict__ Abf,
                                                      const unsigned short* __restrict__ Btbf,
                                                      const float* __restrict__ bias,
                                                      const float* __restrict__ RH,
                                                      unsigned short* __restrict__ CVh,
                                                      unsigned char* __restrict__ valid,
                                                      int* __restrict__ fcnt,
                                                      int* __restrict__ flist) {
    constexpr int K = KDIM;
    __shared__ unsigned short As[2][256 * 64];   // 2 x 32KB
    __shared__ unsigned short Bs[2][256 * 64];   // 2 x 32KB
    const int t = threadIdx.x;                   // 0..511
    const int wave = t >> 6, lane = t & 63;
    const int wm = wave >> 2, wn = wave & 3;     // 2M x 4N wave grid
    const int l16 = lane & 15, quad = lane >> 4;
    const int sw = l16 & 7;                      // read-side XOR key (row&7 == l16&7)

    const int wgid = blockIdx.y * 8 + blockIdx.x;          // 0..511
    const int swz = (wgid & 7) * 64 + (wgid >> 3);
    const int m0 = (swz >> 3) * 256, n0 = (swz & 7) * 256;

    f32x4 zero4 = {0.f, 0.f, 0.f, 0.f};
    f32x4 acc[8][4];
#pragma unroll
    for (int i = 0; i < 8; i++)
#pragma unroll
        for (int j = 0; j < 4; j++) acc[i][j] = zero4;

    // staging roles: rr = row 0..63 (per chunk), gsw = group ^ (row&7)
    const int rr = t >> 3;
    const int gsw = (t ^ rr) & 7;
    const unsigned short* gA = Abf + (size_t)(m0 + rr) * K + gsw * 8;
    const unsigned short* gB = Btbf + (size_t)(n0 + rr) * K + gsw * 8;
    char* lA = (char*)As + (size_t)wave * 1024;  // + buf*32768 + j*8192 (+lane*16 by HW)
    char* lB = (char*)Bs + (size_t)wave * 1024;

    // stage a full A (or B) K-tile: 4 x 8KB chunks, 1 DMA instr per wave per chunk
    auto stageA = [&](int buf, int kn) {
#pragma unroll
        for (int j = 0; j < 4; j++)
            g2l16(gA + (size_t)j * 64 * K + kn, lA + buf * 32768 + j * 8192);
    };
    auto stageB = [&](int buf, int kn) {
#pragma unroll
        for (int j = 0; j < 4; j++)
            g2l16(gB + (size_t)j * 64 * K + kn, lB + buf * 32768 + j * 8192);
    };

    // one phase: pin -> 8 ds_read_b128 -> barrier -> prio MFMA x16 -> barrier
    auto phase = [&](int cur, int mh, int kk4) {
        __builtin_amdgcn_sched_barrier(0);
        const unsigned short* Ab = As[cur];
        const unsigned short* Bb = Bs[cur];
        const int g = (((kk4 + quad) ^ sw) << 3);
        bf16x8 af[4], bfr[4];
#pragma unroll
        for (int mt = 0; mt < 4; mt++)
            af[mt] = *(const bf16x8*)&Ab[(wm * 128 + mh * 64 + mt * 16 + l16) * 64 + g];
#pragma unroll
        for (int nt = 0; nt < 4; nt++)
            bfr[nt] = *(const bf16x8*)&Bb[(wn * 64 + nt * 16 + l16) * 64 + g];
        __builtin_amdgcn_s_barrier();
        __builtin_amdgcn_s_setprio(1);
#pragma unroll
        for (int mt = 0; mt < 4; mt++)
#pragma unroll
            for (int nt = 0; nt < 4; nt++)
                acc[mh * 4 + mt][nt] =
                    __builtin_amdgcn_mfma_f32_16x16x32_bf16(af[mt], bfr[nt], acc[mh * 4 + mt][nt], 0, 0, 0);
        __builtin_amdgcn_s_setprio(0);
        __builtin_amdgcn_s_barrier();
    };

    // prologue: tile 0 -> buf0
    stageB(0, 0);
    stageA(0, 0);
#pragma unroll 1
    for (int tt_ = 0; tt_ < 16; ++tt_) {
        const int cur = tt_ & 1, nxt = cur ^ 1;
        const int kn = (tt_ == 15) ? 960 : (tt_ + 1) * 64;   // tail: dummy restage
        stageB(nxt, kn);
        // tile-start sync: per-wave residency (vmcnt) THEN cross-wave barrier,
        // fenced so no LDS access moves across it at IR/MI level.
        asm volatile("s_waitcnt vmcnt(4)" ::: "memory");
        __builtin_amdgcn_s_barrier();
        asm volatile("" ::: "memory");
        phase(cur, 0, 0);
        stageA(nxt, kn);
        phase(cur, 0, 4);
        phase(cur, 1, 0);
        phase(cur, 1, 4);
    }
    // drain: DMA must not land after LDS dealloc / epilogue
    asm volatile("s_waitcnt vmcnt(0)" ::: "memory");

    // C/D fragment: row = quad*4 + reg, col = l16 (within each 16x16 tile)
    if (n0 < HDIM) {
        // ---- fused dots: this wave's head ----
        const int n = (n0 >> 6) + wn;              // head 0..15
        float rh[4], bv[4];
#pragma unroll
        for (int nt = 0; nt < 4; nt++) {
            int col = n * 64 + nt * 16 + l16;
            rh[nt] = RH[col];
            bv[nt] = bias[col];
        }
#pragma unroll
        for (int mt = 0; mt < 8; mt++) {
#pragma unroll
            for (int r = 0; r < 4; r++) {
                float p = 0.f;
#pragma unroll
                for (int nt = 0; nt < 4; nt++)
                    p += fmaxf(acc[mt][nt][r] + bv[nt], 0.f) * rh[nt];
#pragma unroll
                for (int s = 8; s >= 1; s >>= 1) p += __shfl_xor(p, s, 64);
                if (l16 == 0) {
                    int row = m0 + wm * 128 + mt * 16 + quad * 4 + r;   // b*SEQ + l
                    int b = row >> 11, l = row & (SEQ - 1);
                    valid[((size_t)b * NH + n) * SEQ + l] = (p > 0.5f) ? 1 : 0;
                    if (fabsf(p - 0.5f) < DELTA) {
                        int idx = atomicAdd(fcnt, 1);
                        if (idx < FLAG_CAP) flist[idx] = row * NH + n;
                    }
                }
            }
        }
    } else {
        // ---- V-half: bias + relu, store bf16 to CVh [b][head][l][hd] ----
        const int nv0 = n0 - HDIM;
        const int head = (nv0 >> 6) + wn;          // 0..15 (wave-constant)
        const int b = m0 >> 11;                    // block-constant
        const int l0 = (m0 & (SEQ - 1)) + wm * 128 + quad * 4;
        unsigned short* plane = CVh + ((size_t)(b * NH + head)) * SEQ * HD;
#pragma unroll
        for (int mt = 0; mt < 8; mt++) {
#pragma unroll
            for (int nt = 0; nt < 4; nt++) {
                const int hd = nt * 16 + l16;
                const float bvv = bias[HDIM + nv0 + wn * 64 + hd];
#pragma unroll
                for (int r = 0; r < 4; r++)
                    plane[(size_t)(l0 + mt * 16 + r) * HD + hd] = f2bf(fmaxf(acc[mt][nt][r] + bvv, 0.f));
            }
        }
    }
}

// ---------------- exact fp64 refinement (R6 structure — works) ----------------
__global__ __launch_bounds__(256) void refine_kernel(const float* __restrict__ hs,
                                                     const float* __restrict__ K1w,
                                                     const float* __restrict__ K1b,
                                                     const float* __restrict__ RH,
                                                     const int* __restrict__ fcnt,
                                                     const int* __restrict__ flist,
                                                     unsigned char* __restrict__ valid) {
    int cnt = *fcnt;
    if (cnt > FLAG_CAP) cnt = FLAG_CAP;
    const int wave = threadIdx.x >> 6, d = threadIdx.x & 63;
    const int task = blockIdx.x * 4 + wave;
    if (task >= cnt) return;

    const int code = flist[task];
    const int n = code & (NH - 1);
    const int bl = code >> 4;               // b*SEQ + l
    const float* x = hs + (size_t)bl * HDIM;
    const float* wp = K1w + n * 64 + d;     // stride 1024 over k, lane-coalesced

    double acc0 = 0.0, acc1 = 0.0, acc2 = 0.0, acc3 = 0.0;
    for (int k = 0; k < KDIM; k += 32) {
        float w[32];
#pragma unroll
        for (int u = 0; u < 32; u++)
            w[u] = wp[(size_t)(k + u) * 1024];
        float4 xv[8];
#pragma unroll
        for (int u = 0; u < 8; u++)
            xv[u] = *(const float4*)(x + k + u * 4);
#pragma unroll
        for (int u = 0; u < 8; u++) {
            acc0 += (double)xv[u].x * (double)w[u * 4 + 0];
            acc1 += (double)xv[u].y * (double)w[u * 4 + 1];
            acc2 += (double)xv[u].z * (double)w[u * 4 + 2];
            acc3 += (double)xv[u].w * (double)w[u * 4 + 3];
        }
    }
    double k1 = ((acc0 + acc1) + (acc2 + acc3)) + (double)K1b[n * 64 + d];
    if (k1 < 0.0) k1 = 0.0;
    double contrib = k1 * (double)RH[n * 64 + d];
#pragma unroll
    for (int s = 32; s >= 1; s >>= 1) contrib += __shfl_xor(contrib, s, 64);
    if (d == 0) {
        int b = bl >> 11, l = bl & (SEQ - 1);
        valid[((size_t)b * NH + n) * SEQ + l] = (contrib > 0.5) ? 1 : 0;
    }
}

// ---------------- nearest-valid scans ----------------
__global__ __launch_bounds__(64) void scan_kernel(const unsigned char* __restrict__ valid,
                                                  ushort4* __restrict__ maps) {
    int bn = blockIdx.x;                 // b*NH + n
    int b = bn >> 4, n = bn & (NH - 1);
    int lane = threadIdx.x;
    __shared__ unsigned int summ[64];

    const unsigned char* vp = valid + (size_t)bn * SEQ + lane * 32;
    uint4 c0 = *(const uint4*)vp;
    uint4 c1 = *(const uint4*)(vp + 16);
    unsigned int wds[8] = {c0.x, c0.y, c0.z, c0.w, c1.x, c1.y, c1.z, c1.w};
    unsigned int mask = 0;
#pragma unroll
    for (int i = 0; i < 8; i++) {
#pragma unroll
        for (int j = 0; j < 4; j++)
            mask |= (((wds[i] >> (8 * j)) & 0xffu) ? 1u : 0u) << (i * 4 + j);
    }

    // ---- forward ----
    int cnt = 0, va = 0, vb = 0;
#pragma unroll
    for (int tt = 0; tt < 32; tt++) {
        if (mask & (1u << tt)) { vb = va; va = lane * 32 + tt; cnt++; }
    }
    summ[lane] = (unsigned)((cnt > 2 ? 2 : cnt) | (va << 2) | (vb << 13));
    __syncthreads();
    int a = 0, bb_ = 0;
    for (int tt = 0; tt < lane; tt++) {
        unsigned s = summ[tt];
        int c = s & 3, sva = (s >> 2) & 2047, svb = (s >> 13) & 2047;
        if (c >= 2) { a = sva; bb_ = svb; }
        else if (c == 1) { bb_ = a; a = sva; }
    }
    unsigned int fres[32];
#pragma unroll
    for (int tt = 0; tt < 32; tt++) {
        if (mask & (1u << tt)) { bb_ = a; a = lane * 32 + tt; }
        fres[tt] = (unsigned)a | ((unsigned)bb_ << 16);
    }
    __syncthreads();

    // ---- backward (mirrored values) ----
    unsigned int maskb = mask;
    if (lane == 63) maskb &= ~(1u << 31);   // exclude j = L-1
    cnt = 0; va = 0; vb = 0;
#pragma unroll
    for (int tt = 31; tt >= 0; tt--) {
        if (maskb & (1u << tt)) { vb = va; va = (SEQ - 1) - (lane * 32 + tt); cnt++; }
    }
    summ[lane] = (unsigned)((cnt > 2 ? 2 : cnt) | (va << 2) | (vb << 13));
    __syncthreads();
    int a2 = SEQ - 1, b2 = SEQ - 1;
    for (int tt = 63; tt > lane; tt--) {
        unsigned s = summ[tt];
        int c = s & 3, sva = (s >> 2) & 2047, svb = (s >> 13) & 2047;
        if (c >= 2) { a2 = sva; b2 = svb; }
        else if (c == 1) { b2 = a2; a2 = sva; }
    }
#pragma unroll
    for (int tt = 31; tt >= 0; tt--) {
        int j = lane * 32 + tt;
        if (maskb & (1u << tt)) { b2 = a2; a2 = (SEQ - 1) - j; }
        unsigned f = fres[tt];
        maps[((size_t)b * SEQ + j) * NH + n] =
            make_ushort4((unsigned short)(f & 0xffffu), (unsigned short)(f >> 16),
                         (unsigned short)a2, (unsigned short)b2);
    }
}

// ---------------- gather + weighted sum (CVh bf16 [b][head][l][hd]) ----------------
__global__ __launch_bounds__(256) void gather_kernel(const unsigned short* __restrict__ CVh,
                                                     const ushort4* __restrict__ maps,
                                                     const float* __restrict__ bw,
                                                     float* __restrict__ out) {
    int bl = blockIdx.x;
    int t = threadIdx.x, n = t >> 4, q = t & 15;
    int b = bl >> 11;
    ushort4 m = maps[(size_t)bl * NH + n];
    const float4 w = *(const float4*)&bw[n * 4];
    const unsigned short* plane = CVh + ((size_t)(b * NH + n)) * SEQ * HD + q * 4;
    const ushort4 u0 = *(const ushort4*)&plane[(size_t)m.x * HD];
    const ushort4 u1 = *(const ushort4*)&plane[(size_t)m.y * HD];
    const ushort4 u2 = *(const ushort4*)&plane[(size_t)m.z * HD];
    const ushort4 u3 = *(const ushort4*)&plane[(size_t)m.w * HD];
    float4 o;
    o.x = w.x * bf2f(u0.x) + w.y * bf2f(u1.x) + w.z * bf2f(u2.x) + w.w * bf2f(u3.x);
    o.y = w.x * bf2f(u0.y) + w.y * bf2f(u1.y) + w.z * bf2f(u2.y) + w.w * bf2f(u3.y);
    o.z = w.x * bf2f(u0.z) + w.y * bf2f(u1.z) + w.z * bf2f(u2.z) + w.w * bf2f(u3.z);
    o.w = w.x * bf2f(u0.w) + w.y * bf2f(u1.w) + w.z * bf2f(u2.w) + w.w * bf2f(u3.w);
    *(float4*)&out[(size_t)bl * (NH * HD) + n * 64 + q * 4] = o;
}

// ---------------- launch ----------------
extern "C" void kernel_launch(void* const* d_in, const int* in_sizes, int n_in,
                              void* d_out, int out_size, void* d_ws, size_t ws_size,
                              hipStream_t stream) {
    (void)in_sizes; (void)n_in; (void)out_size; (void)ws_size;
    const float* hs  = (const float*)d_in[0];
    const float* K1w = (const float*)d_in[1];
    const float* K1b = (const float*)d_in[2];
    const float* V1w = (const float*)d_in[3];
    const float* V1b = (const float*)d_in[4];
    const float* bw  = (const float*)d_in[5];
    const float* RH  = (const float*)d_in[6];
    float* out = (float*)d_out;
    char* ws = (char*)d_ws;

    unsigned short* Abf  = (unsigned short*)(ws + OFF_A);
    unsigned short* Btbf = (unsigned short*)(ws + OFF_BT);
    int* fcnt = (int*)(ws + OFF_FCNT);
    int* flist = (int*)(ws + OFF_FLIST);
    float* bias  = (float*)(ws + OFF_BIAS);
    unsigned short* CVh = (unsigned short*)(ws + OFF_CVH);
    unsigned char* valid = (unsigned char*)(ws + OFF_VALID);
    ushort4* maps = (ushort4*)(ws + OFF_MAPS);

    prep_kernel<<<18440, 256, 0, stream>>>((const float4*)hs, (ushort4*)Abf,
                                           K1w, V1w, Btbf, K1b, V1b, bias, fcnt);
    gemm_kernel<<<dim3(N_COLS / 256, M_ROWS / 256), 512, 0, stream>>>(
        Abf, Btbf, bias, RH, CVh, valid, fcnt, flist);
    refine_kernel<<<FLAG_CAP / 4, 256, 0, stream>>>(
        hs, K1w, K1b, RH, fcnt, flist, valid);
    scan_kernel<<<BS * NH, 64, 0, stream>>>(valid, maps);
    gather_kernel<<<BS * SEQ, 256, 0, stream>>>(CVh, maps, bw, out);
}

// Round 6
// 372.932 us; speedup vs baseline: 1.0748x; 1.0748x over previous
//
#include <hip/hip_runtime.h>
#include <hip/hip_bf16.h>
#include <cstdint>

// ---------------- problem dims ----------------
#define BS 8
#define SEQ 2048
#define HDIM 1024
#define NH 16
#define HD 64
#define M_ROWS (BS * SEQ)   // 16384
#define N_COLS (2 * HDIM)   // 2048 GEMM cols: 0..1023 = K1 (dots only), 1024..2047 = V1
#define KDIM HDIM           // 1024

#define DELTA 0.025f
#define FLAG_CAP 32768           // flat flagged-task list; expected ~6200 total

// ---------------- workspace layout (bytes) ----------------
#define OFF_A      ((size_t)0)           // bf16 A [M,K]             33,554,432
#define OFF_BT     ((size_t)33554432)    // bf16 Bt [N,K]             4,194,304
#define OFF_FCNT   ((size_t)37748736)    // int
#define OFF_FLIST  ((size_t)37748800)    // int[FLAG_CAP]               131,072
#define OFF_BIAS   ((size_t)37879872)    // f32 [2048]
#define OFF_CVH    ((size_t)41943040)    // bf16 CV [M,1024]          33,554,432
#define OFF_VALID  ((size_t)75497472)    // u8 [BS][NH][SEQ]             262,144
#define OFF_MAPS   ((size_t)75759616)    // ushort4 [BS][SEQ][NH]      2,097,152
// total ~78 MB

typedef __attribute__((ext_vector_type(8))) __bf16 bf16x8;
typedef __attribute__((ext_vector_type(4))) float f32x4;

// float -> bf16 bits, round-to-nearest-even (inputs are finite)
__device__ __forceinline__ unsigned short f2bf(float f) {
    unsigned int x = __builtin_bit_cast(unsigned int, f);
    unsigned int r = x + 0x7fffu + ((x >> 16) & 1u);
    return (unsigned short)(r >> 16);
}
__device__ __forceinline__ float bf2f(unsigned short u) {
    return __builtin_bit_cast(float, (unsigned int)u << 16);
}

// async 16B global -> LDS (dest = wave-uniform LDS base + lane*16)
__device__ __forceinline__ void g2l16(const void* gp, void* lp) {
    __builtin_amdgcn_global_load_lds(
        (__attribute__((address_space(1))) void*)(void*)gp,
        (__attribute__((address_space(3))) void*)lp, 16, 0, 0);
}

// ---------------- fused prep: hs->bf16 | W transpose->bf16 | bias+fcnt ----------------
// section 1 widened vs R0: 2x float4 in -> packed uint4 (16B) out per thread.
__global__ __launch_bounds__(256) void prep_kernel(const float4* __restrict__ hs4,
                                                   unsigned short* __restrict__ Abf,
                                                   const float* __restrict__ K1w,
                                                   const float* __restrict__ V1w,
                                                   unsigned short* __restrict__ Bt,
                                                   const float* __restrict__ K1b,
                                                   const float* __restrict__ V1b,
                                                   float* __restrict__ bias,
                                                   int* __restrict__ fcnt) {
    __shared__ float tile[32][33];
    const int blk = blockIdx.x;
    const int t = threadIdx.x;
    if (blk < 8192) {
        int i = blk * 256 + t;            // 2,097,152 uint4 stores
        float4 v0 = hs4[i * 2];
        float4 v1 = hs4[i * 2 + 1];
        uint4 o;
        o.x = (unsigned)f2bf(v0.x) | ((unsigned)f2bf(v0.y) << 16);
        o.y = (unsigned)f2bf(v0.z) | ((unsigned)f2bf(v0.w) << 16);
        o.z = (unsigned)f2bf(v1.x) | ((unsigned)f2bf(v1.y) << 16);
        o.w = (unsigned)f2bf(v1.z) | ((unsigned)f2bf(v1.w) << 16);
        ((uint4*)Abf)[i] = o;
    } else if (blk < 10240) {
        int lb = blk - 8192;              // 0..2047 = tn + 32*tk + 1024*z
        int z = lb >> 10;
        int tk = (lb >> 5) & 31;
        int tn = lb & 31;
        const float* W = z ? V1w : K1w;
        int r = t >> 3;                   // 0..31
        int c4 = (t & 7) * 4;             // 0,4,..,28
        const float4 v = *(const float4*)&W[(size_t)(tk * 32 + r) * 1024 + tn * 32 + c4];
        tile[r][c4 + 0] = v.x; tile[r][c4 + 1] = v.y;
        tile[r][c4 + 2] = v.z; tile[r][c4 + 3] = v.w;
        __syncthreads();
        int n = tn * 32 + r;
        int k = tk * 32 + c4;
        ushort4 o;
        o.x = f2bf(tile[c4 + 0][r]); o.y = f2bf(tile[c4 + 1][r]);
        o.z = f2bf(tile[c4 + 2][r]); o.w = f2bf(tile[c4 + 3][r]);
        *(ushort4*)&Bt[((size_t)z * 1024 + n) * 1024 + k] = o;
    } else {
        int i = (blk - 10240) * 256 + t;  // 0..2047
        bias[i] = (i < 1024) ? K1b[i] : V1b[i - 1024];
        if (i == 0) *fcnt = 0;
    }
}

// ---------------- GEMM + fused dots (R0 structure, + T1 XCD swizzle) ----------------
// A [M,K] bf16, Bt [N,K] bf16. 128x128 tile, BK=64, 4 waves 2x2, 16 K-iters.
// LDS rows are 128 B; to avoid 16-way bank conflicts under global_load_lds's
// lane-ordered dest, the SOURCE k-group is XOR-swizzled: physical 16B-group
// g for row r holds logical group g^(r&7). Fragment reads apply the same XOR
// -> 16 lanes span 8 bank-groups (2-way, free). Permutation stays within each
// row's 128 B so global coalescing is unchanged.
// T1 XCD swizzle (2048 wgs % 8 == 0, bijective): HW round-robins consecutive
// dispatch ids across 8 XCDs; remap so XCD k owns logical blocks
// [256k, 256k+256) = m-tiles [16k,16k+16) x all 16 n-tiles. The 16 n-tiles
// sharing an A-panel now run on ONE XCD -> A-panel L2-local (16x reuse)
// instead of replicated into 8 L2s / re-fetched from L3/HBM.
// n0 <  1024: fused dots epilogue (valid + flag list), K-half never stored.
// n0 >= 1024: relu(acc+bias) -> CVh (bf16) [M][1024].
__global__ __launch_bounds__(256) void gemm_kernel(const unsigned short* __restrict__ Abf,
                                                   const unsigned short* __restrict__ Btbf,
                                                   const float* __restrict__ bias,
                                                   const float* __restrict__ RH,
                                                   unsigned short* __restrict__ CVh,
                                                   unsigned char* __restrict__ valid,
                                                   int* __restrict__ fcnt,
                                                   int* __restrict__ flist) {
    constexpr int K = KDIM, BK = 64;
    __shared__ unsigned short As[128 * BK];   // [row][64] with XOR-swizzled groups
    __shared__ unsigned short Bs[128 * BK];
    const int t = threadIdx.x;
    const int wave = t >> 6, lane = t & 63;
    const int wm = wave >> 1, wn = wave & 1;
    const int l16 = lane & 15, quad = lane >> 4;
    const int sw = l16 & 7;                  // read-side XOR key (r&7 == l16&7)

    // T1: bijective XCD-contiguous remap of the 16x128 tile grid
    const int wgid = blockIdx.y * 16 + blockIdx.x;      // 0..2047, x-fastest
    const int swz = (wgid & 7) * 256 + (wgid >> 3);
    const int m0 = (swz >> 4) * 128, n0 = (swz & 15) * 128;

    f32x4 zero4 = {0.f, 0.f, 0.f, 0.f};
    f32x4 acc[4][4];
#pragma unroll
    for (int i = 0; i < 4; i++)
#pragma unroll
        for (int j = 0; j < 4; j++) acc[i][j] = zero4;

    // staging roles: rr = row 0..31 (per issue), g = 16B-group 0..7
    const int rr = t >> 3;
    const int gsw = (t ^ (t >> 3)) & 7;      // g ^ (row&7); row&7 invariant across issues
    const unsigned short* gA = Abf + (size_t)(m0 + rr) * K + gsw * 8;
    const unsigned short* gB = Btbf + (size_t)(n0 + rr) * K + gsw * 8;
    char* lAs = (char*)As + (size_t)wave * 1024;
    char* lBs = (char*)Bs + (size_t)wave * 1024;

    for (int k0 = 0; k0 < K; k0 += BK) {
#pragma unroll
        for (int i = 0; i < 4; i++)
            g2l16(gA + (size_t)i * 32 * K + k0, lAs + i * 4096);
#pragma unroll
        for (int i = 0; i < 4; i++)
            g2l16(gB + (size_t)i * 32 * K + k0, lBs + i * 4096);
        __syncthreads();   // drains global_load_lds (vmcnt) + barrier
#pragma unroll
        for (int h = 0; h < 2; h++) {
            bf16x8 af[4], bfr[4];
            const int hq = h * 4 + quad;
#pragma unroll
            for (int mt = 0; mt < 4; mt++)
                af[mt] = *(const bf16x8*)&As[(wm * 64 + mt * 16 + l16) * BK + (hq ^ sw) * 8];
#pragma unroll
            for (int nt = 0; nt < 4; nt++)
                bfr[nt] = *(const bf16x8*)&Bs[(wn * 64 + nt * 16 + l16) * BK + (hq ^ sw) * 8];
#pragma unroll
            for (int mt = 0; mt < 4; mt++)
#pragma unroll
                for (int nt = 0; nt < 4; nt++)
                    acc[mt][nt] = __builtin_amdgcn_mfma_f32_16x16x32_bf16(af[mt], bfr[nt], acc[mt][nt], 0, 0, 0);
        }
        __syncthreads();
    }
    // C/D fragment: row = quad*4 + reg, col = l16 (within each 16x16 tile)
    if (n0 < HDIM) {
        // ---- fused dots: this wave's head ----
        const int n = (n0 >> 6) + wn;
        float rh[4], bv[4];
#pragma unroll
        for (int nt = 0; nt < 4; nt++) {
            int col = n * 64 + nt * 16 + l16;
            rh[nt] = RH[col];
            bv[nt] = bias[col];
        }
#pragma unroll
        for (int mt = 0; mt < 4; mt++) {
#pragma unroll
            for (int r = 0; r < 4; r++) {
                float p = 0.f;
#pragma unroll
                for (int nt = 0; nt < 4; nt++)
                    p += fmaxf(acc[mt][nt][r] + bv[nt], 0.f) * rh[nt];
#pragma unroll
                for (int s = 8; s >= 1; s >>= 1) p += __shfl_xor(p, s, 64);
                if (l16 == 0) {
                    int row = m0 + wm * 64 + mt * 16 + quad * 4 + r;   // b*SEQ + l
                    int b = row >> 11, l = row & (SEQ - 1);
                    valid[((size_t)b * NH + n) * SEQ + l] = (p > 0.5f) ? 1 : 0;
                    if (fabsf(p - 0.5f) < DELTA) {
                        int idx = atomicAdd(fcnt, 1);
                        if (idx < FLAG_CAP) flist[idx] = row * NH + n;
                    }
                }
            }
        }
    } else {
        // ---- V-half: bias + relu, store bf16 to CVh ----
        const int nv0 = n0 - HDIM;
#pragma unroll
        for (int mt = 0; mt < 4; mt++) {
            int gm = m0 + wm * 64 + mt * 16 + quad * 4;
#pragma unroll
            for (int nt = 0; nt < 4; nt++) {
                int gn = nv0 + wn * 64 + nt * 16 + l16;
                float bvv = bias[HDIM + gn];
#pragma unroll
                for (int r = 0; r < 4; r++)
                    CVh[(size_t)(gm + r) * HDIM + gn] = f2bf(fmaxf(acc[mt][nt][r] + bvv, 0.f));
            }
        }
    }
}

// ---------------- exact fp64 refinement (R6 structure — works) ----------------
// Flat task list; 4 waves/block, ONE task per wave. Intra-iteration latency
// hiding: 32 independent weight dwords + 8 uniform float4 x's per k-group,
// one waitcnt, then 32 v_fma_f64.
__global__ __launch_bounds__(256) void refine_kernel(const float* __restrict__ hs,
                                                     const float* __restrict__ K1w,
                                                     const float* __restrict__ K1b,
                                                     const float* __restrict__ RH,
                                                     const int* __restrict__ fcnt,
                                                     const int* __restrict__ flist,
                                                     unsigned char* __restrict__ valid) {
    int cnt = *fcnt;
    if (cnt > FLAG_CAP) cnt = FLAG_CAP;
    const int wave = threadIdx.x >> 6, d = threadIdx.x & 63;
    const int task = blockIdx.x * 4 + wave;
    if (task >= cnt) return;

    const int code = flist[task];
    const int n = code & (NH - 1);
    const int bl = code >> 4;               // b*SEQ + l
    const float* x = hs + (size_t)bl * HDIM;
    const float* wp = K1w + n * 64 + d;     // stride 1024 over k, lane-coalesced

    double acc0 = 0.0, acc1 = 0.0, acc2 = 0.0, acc3 = 0.0;
    for (int k = 0; k < KDIM; k += 32) {
        float w[32];
#pragma unroll
        for (int u = 0; u < 32; u++)
            w[u] = wp[(size_t)(k + u) * 1024];
        float4 xv[8];
#pragma unroll
        for (int u = 0; u < 8; u++)
            xv[u] = *(const float4*)(x + k + u * 4);
#pragma unroll
        for (int u = 0; u < 8; u++) {
            acc0 += (double)xv[u].x * (double)w[u * 4 + 0];
            acc1 += (double)xv[u].y * (double)w[u * 4 + 1];
            acc2 += (double)xv[u].z * (double)w[u * 4 + 2];
            acc3 += (double)xv[u].w * (double)w[u * 4 + 3];
        }
    }
    double k1 = ((acc0 + acc1) + (acc2 + acc3)) + (double)K1b[n * 64 + d];
    if (k1 < 0.0) k1 = 0.0;
    double contrib = k1 * (double)RH[n * 64 + d];
#pragma unroll
    for (int s = 32; s >= 1; s >>= 1) contrib += __shfl_xor(contrib, s, 64);
    if (d == 0) {
        int b = bl >> 11, l = bl & (SEQ - 1);
        valid[((size_t)b * NH + n) * SEQ + l] = (contrib > 0.5) ? 1 : 0;
    }
}

// ---------------- nearest-valid scans ----------------
// one block (64 threads) per (b,n). Lane i owns positions [32i, 32i+32).
__global__ __launch_bounds__(64) void scan_kernel(const unsigned char* __restrict__ valid,
                                                  ushort4* __restrict__ maps) {
    int bn = blockIdx.x;                 // b*NH + n
    int b = bn >> 4, n = bn & (NH - 1);
    int lane = threadIdx.x;
    __shared__ unsigned int summ[64];

    const unsigned char* vp = valid + (size_t)bn * SEQ + lane * 32;
    uint4 c0 = *(const uint4*)vp;
    uint4 c1 = *(const uint4*)(vp + 16);
    unsigned int wds[8] = {c0.x, c0.y, c0.z, c0.w, c1.x, c1.y, c1.z, c1.w};
    unsigned int mask = 0;
#pragma unroll
    for (int i = 0; i < 8; i++) {
#pragma unroll
        for (int j = 0; j < 4; j++)
            mask |= (((wds[i] >> (8 * j)) & 0xffu) ? 1u : 0u) << (i * 4 + j);
    }

    // ---- forward ----
    int cnt = 0, va = 0, vb = 0;
#pragma unroll
    for (int tt = 0; tt < 32; tt++) {
        if (mask & (1u << tt)) { vb = va; va = lane * 32 + tt; cnt++; }
    }
    summ[lane] = (unsigned)((cnt > 2 ? 2 : cnt) | (va << 2) | (vb << 13));
    __syncthreads();
    int a = 0, bb_ = 0;
    for (int tt = 0; tt < lane; tt++) {
        unsigned s = summ[tt];
        int c = s & 3, sva = (s >> 2) & 2047, svb = (s >> 13) & 2047;
        if (c >= 2) { a = sva; bb_ = svb; }
        else if (c == 1) { bb_ = a; a = sva; }
    }
    unsigned int fres[32];
#pragma unroll
    for (int tt = 0; tt < 32; tt++) {
        if (mask & (1u << tt)) { bb_ = a; a = lane * 32 + tt; }
        fres[tt] = (unsigned)a | ((unsigned)bb_ << 16);
    }
    __syncthreads();

    // ---- backward (mirrored values) ----
    unsigned int maskb = mask;
    if (lane == 63) maskb &= ~(1u << 31);   // exclude j = L-1
    cnt = 0; va = 0; vb = 0;
#pragma unroll
    for (int tt = 31; tt >= 0; tt--) {
        if (maskb & (1u << tt)) { vb = va; va = (SEQ - 1) - (lane * 32 + tt); cnt++; }
    }
    summ[lane] = (unsigned)((cnt > 2 ? 2 : cnt) | (va << 2) | (vb << 13));
    __syncthreads();
    int a2 = SEQ - 1, b2 = SEQ - 1;
    for (int tt = 63; tt > lane; tt--) {
        unsigned s = summ[tt];
        int c = s & 3, sva = (s >> 2) & 2047, svb = (s >> 13) & 2047;
        if (c >= 2) { a2 = sva; b2 = svb; }
        else if (c == 1) { b2 = a2; a2 = sva; }
    }
#pragma unroll
    for (int tt = 31; tt >= 0; tt--) {
        int j = lane * 32 + tt;
        if (maskb & (1u << tt)) { b2 = a2; a2 = (SEQ - 1) - j; }
        unsigned f = fres[tt];
        maps[((size_t)b * SEQ + j) * NH + n] =
            make_ushort4((unsigned short)(f & 0xffffu), (unsigned short)(f >> 16),
                         (unsigned short)a2, (unsigned short)b2);
    }
}

// ---------------- gather + weighted sum (CVh bf16 [M][1024]) ----------------
__global__ __launch_bounds__(256) void gather_kernel(const unsigned short* __restrict__ CVh,
                                                     const ushort4* __restrict__ maps,
                                                     const float* __restrict__ bw,
                                                     float* __restrict__ out) {
    int bl = blockIdx.x;
    int t = threadIdx.x, n = t >> 4, q = t & 15;
    int b = bl >> 11;
    ushort4 m = maps[(size_t)bl * NH + n];
    const float4 w = *(const float4*)&bw[n * 4];
    size_t colbase = (size_t)(n * 64 + q * 4);
    size_t rowb = (size_t)b * SEQ;
    const ushort4 u0 = *(const ushort4*)&CVh[(rowb + m.x) * HDIM + colbase];
    const ushort4 u1 = *(const ushort4*)&CVh[(rowb + m.y) * HDIM + colbase];
    const ushort4 u2 = *(const ushort4*)&CVh[(rowb + m.z) * HDIM + colbase];
    const ushort4 u3 = *(const ushort4*)&CVh[(rowb + m.w) * HDIM + colbase];
    float4 o;
    o.x = w.x * bf2f(u0.x) + w.y * bf2f(u1.x) + w.z * bf2f(u2.x) + w.w * bf2f(u3.x);
    o.y = w.x * bf2f(u0.y) + w.y * bf2f(u1.y) + w.z * bf2f(u2.y) + w.w * bf2f(u3.y);
    o.z = w.x * bf2f(u0.z) + w.y * bf2f(u1.z) + w.z * bf2f(u2.z) + w.w * bf2f(u3.z);
    o.w = w.x * bf2f(u0.w) + w.y * bf2f(u1.w) + w.z * bf2f(u2.w) + w.w * bf2f(u3.w);
    *(float4*)&out[(size_t)bl * (NH * HD) + n * 64 + q * 4] = o;
}

// ---------------- launch ----------------
extern "C" void kernel_launch(void* const* d_in, const int* in_sizes, int n_in,
                              void* d_out, int out_size, void* d_ws, size_t ws_size,
                              hipStream_t stream) {
    (void)in_sizes; (void)n_in; (void)out_size; (void)ws_size;
    const float* hs  = (const float*)d_in[0];
    const float* K1w = (const float*)d_in[1];
    const float* K1b = (const float*)d_in[2];
    const float* V1w = (const float*)d_in[3];
    const float* V1b = (const float*)d_in[4];
    const float* bw  = (const float*)d_in[5];
    const float* RH  = (const float*)d_in[6];
    float* out = (float*)d_out;
    char* ws = (char*)d_ws;

    unsigned short* Abf  = (unsigned short*)(ws + OFF_A);
    unsigned short* Btbf = (unsigned short*)(ws + OFF_BT);
    int* fcnt = (int*)(ws + OFF_FCNT);
    int* flist = (int*)(ws + OFF_FLIST);
    float* bias  = (float*)(ws + OFF_BIAS);
    unsigned short* CVh = (unsigned short*)(ws + OFF_CVH);
    unsigned char* valid = (unsigned char*)(ws + OFF_VALID);
    ushort4* maps = (ushort4*)(ws + OFF_MAPS);

    prep_kernel<<<10248, 256, 0, stream>>>((const float4*)hs, Abf,
                                           K1w, V1w, Btbf, K1b, V1b, bias, fcnt);
    gemm_kernel<<<dim3(N_COLS / 128, M_ROWS / 128), 256, 0, stream>>>(
        Abf, Btbf, bias, RH, CVh, valid, fcnt, flist);
    refine_kernel<<<FLAG_CAP / 4, 256, 0, stream>>>(
        hs, K1w, K1b, RH, fcnt, flist, valid);
    scan_kernel<<<BS * NH, 64, 0, stream>>>(valid, maps);
    gather_kernel<<<BS * SEQ, 256, 0, stream>>>(CVh, maps, bw, out);
}

// Round 7
// 350.278 us; speedup vs baseline: 1.1444x; 1.0647x over previous
//
#include <hip/hip_runtime.h>
#include <hip/hip_bf16.h>
#include <cstdint>

// ---------------- problem dims ----------------
#define BS 8
#define SEQ 2048
#define HDIM 1024
#define NH 16
#define HD 64
#define M_ROWS (BS * SEQ)   // 16384
#define N_COLS (2 * HDIM)   // 2048 GEMM cols: 0..1023 = K1 (dots only), 1024..2047 = V1
#define KDIM HDIM           // 1024

#define DELTA 0.025f
#define PERH_CAP 2048            // per-head flagged-task list; expected ~390/head

// ---------------- workspace layout (bytes) ----------------
#define OFF_A      ((size_t)0)           // bf16 A [M,K]             33,554,432
#define OFF_BT     ((size_t)33554432)    // bf16 Bt [N,K]             4,194,304
#define OFF_FCNT   ((size_t)37748736)    // int[16]
#define OFF_FLIST  ((size_t)37748800)    // int[16][2048]               131,072
#define OFF_BIAS   ((size_t)37879872)    // f32 [2048]
#define OFF_CVH    ((size_t)41943040)    // bf16 CV [M,1024]          33,554,432
#define OFF_VALID  ((size_t)75497472)    // u8 [BS][NH][SEQ]             262,144
#define OFF_MAPS   ((size_t)75759616)    // ushort4 [BS][SEQ][NH]      2,097,152
// total ~78 MB

typedef __attribute__((ext_vector_type(8))) __bf16 bf16x8;
typedef __attribute__((ext_vector_type(4))) float f32x4;

// float -> bf16 bits, round-to-nearest-even (inputs are finite)
__device__ __forceinline__ unsigned short f2bf(float f) {
    unsigned int x = __builtin_bit_cast(unsigned int, f);
    unsigned int r = x + 0x7fffu + ((x >> 16) & 1u);
    return (unsigned short)(r >> 16);
}
__device__ __forceinline__ float bf2f(unsigned short u) {
    return __builtin_bit_cast(float, (unsigned int)u << 16);
}

// async 16B global -> LDS (dest = wave-uniform LDS base + lane*16)
__device__ __forceinline__ void g2l16(const void* gp, void* lp) {
    __builtin_amdgcn_global_load_lds(
        (__attribute__((address_space(1))) void*)(void*)gp,
        (__attribute__((address_space(3))) void*)lp, 16, 0, 0);
}

// ---------------- fused prep: hs->bf16 | W transpose->bf16 | bias+fcnt ----------------
__global__ __launch_bounds__(256) void prep_kernel(const float4* __restrict__ hs4,
                                                   unsigned short* __restrict__ Abf,
                                                   const float* __restrict__ K1w,
                                                   const float* __restrict__ V1w,
                                                   unsigned short* __restrict__ Bt,
                                                   const float* __restrict__ K1b,
                                                   const float* __restrict__ V1b,
                                                   float* __restrict__ bias,
                                                   int* __restrict__ fcnt) {
    __shared__ float tile[32][33];
    const int blk = blockIdx.x;
    const int t = threadIdx.x;
    if (blk < 8192) {
        int i = blk * 256 + t;            // 2,097,152 uint4 stores
        float4 v0 = hs4[i * 2];
        float4 v1 = hs4[i * 2 + 1];
        uint4 o;
        o.x = (unsigned)f2bf(v0.x) | ((unsigned)f2bf(v0.y) << 16);
        o.y = (unsigned)f2bf(v0.z) | ((unsigned)f2bf(v0.w) << 16);
        o.z = (unsigned)f2bf(v1.x) | ((unsigned)f2bf(v1.y) << 16);
        o.w = (unsigned)f2bf(v1.z) | ((unsigned)f2bf(v1.w) << 16);
        ((uint4*)Abf)[i] = o;
    } else if (blk < 10240) {
        int lb = blk - 8192;              // 0..2047 = tn + 32*tk + 1024*z
        int z = lb >> 10;
        int tk = (lb >> 5) & 31;
        int tn = lb & 31;
        const float* W = z ? V1w : K1w;
        int r = t >> 3;                   // 0..31
        int c4 = (t & 7) * 4;             // 0,4,..,28
        const float4 v = *(const float4*)&W[(size_t)(tk * 32 + r) * 1024 + tn * 32 + c4];
        tile[r][c4 + 0] = v.x; tile[r][c4 + 1] = v.y;
        tile[r][c4 + 2] = v.z; tile[r][c4 + 3] = v.w;
        __syncthreads();
        int n = tn * 32 + r;
        int k = tk * 32 + c4;
        ushort4 o;
        o.x = f2bf(tile[c4 + 0][r]); o.y = f2bf(tile[c4 + 1][r]);
        o.z = f2bf(tile[c4 + 2][r]); o.w = f2bf(tile[c4 + 3][r]);
        *(ushort4*)&Bt[((size_t)z * 1024 + n) * 1024 + k] = o;
    } else {
        int i = (blk - 10240) * 256 + t;  // 0..2047
        bias[i] = (i < 1024) ? K1b[i] : V1b[i - 1024];
        if (i < 16) fcnt[i] = 0;
    }
}

// ---------------- GEMM + fused dots (R0 structure + T1 XCD swizzle) ----------------
// A [M,K] bf16, Bt [N,K] bf16. 128x128 tile, BK=64, 4 waves 2x2, 16 K-iters.
// XOR-swizzled staging (verified, 0 bank conflicts). T1 bijective XCD remap
// (confirmed: FETCH 139->82 MB; time-neutral but kept for the traffic win).
// n0 <  1024: fused dots epilogue -> valid + PER-HEAD flag lists.
// n0 >= 1024: relu(acc+bias) -> CVh (bf16) [M][1024].
__global__ __launch_bounds__(256) void gemm_kernel(const unsigned short* __restrict__ Abf,
                                                   const unsigned short* __restrict__ Btbf,
                                                   const float* __restrict__ bias,
                                                   const float* __restrict__ RH,
                                                   unsigned short* __restrict__ CVh,
                                                   unsigned char* __restrict__ valid,
                                                   int* __restrict__ fcnt,
                                                   int* __restrict__ flist) {
    constexpr int K = KDIM, BK = 64;
    __shared__ unsigned short As[128 * BK];   // [row][64] with XOR-swizzled groups
    __shared__ unsigned short Bs[128 * BK];
    const int t = threadIdx.x;
    const int wave = t >> 6, lane = t & 63;
    const int wm = wave >> 1, wn = wave & 1;
    const int l16 = lane & 15, quad = lane >> 4;
    const int sw = l16 & 7;                  // read-side XOR key (r&7 == l16&7)

    // T1: bijective XCD-contiguous remap of the 16x128 tile grid
    const int wgid = blockIdx.y * 16 + blockIdx.x;      // 0..2047, x-fastest
    const int swz = (wgid & 7) * 256 + (wgid >> 3);
    const int m0 = (swz >> 4) * 128, n0 = (swz & 15) * 128;

    f32x4 zero4 = {0.f, 0.f, 0.f, 0.f};
    f32x4 acc[4][4];
#pragma unroll
    for (int i = 0; i < 4; i++)
#pragma unroll
        for (int j = 0; j < 4; j++) acc[i][j] = zero4;

    // staging roles: rr = row 0..31 (per issue), g = 16B-group 0..7
    const int rr = t >> 3;
    const int gsw = (t ^ (t >> 3)) & 7;      // g ^ (row&7); row&7 invariant across issues
    const unsigned short* gA = Abf + (size_t)(m0 + rr) * K + gsw * 8;
    const unsigned short* gB = Btbf + (size_t)(n0 + rr) * K + gsw * 8;
    char* lAs = (char*)As + (size_t)wave * 1024;
    char* lBs = (char*)Bs + (size_t)wave * 1024;

    for (int k0 = 0; k0 < K; k0 += BK) {
#pragma unroll
        for (int i = 0; i < 4; i++)
            g2l16(gA + (size_t)i * 32 * K + k0, lAs + i * 4096);
#pragma unroll
        for (int i = 0; i < 4; i++)
            g2l16(gB + (size_t)i * 32 * K + k0, lBs + i * 4096);
        __syncthreads();   // drains global_load_lds (vmcnt) + barrier
#pragma unroll
        for (int h = 0; h < 2; h++) {
            bf16x8 af[4], bfr[4];
            const int hq = h * 4 + quad;
#pragma unroll
            for (int mt = 0; mt < 4; mt++)
                af[mt] = *(const bf16x8*)&As[(wm * 64 + mt * 16 + l16) * BK + (hq ^ sw) * 8];
#pragma unroll
            for (int nt = 0; nt < 4; nt++)
                bfr[nt] = *(const bf16x8*)&Bs[(wn * 64 + nt * 16 + l16) * BK + (hq ^ sw) * 8];
#pragma unroll
            for (int mt = 0; mt < 4; mt++)
#pragma unroll
                for (int nt = 0; nt < 4; nt++)
                    acc[mt][nt] = __builtin_amdgcn_mfma_f32_16x16x32_bf16(af[mt], bfr[nt], acc[mt][nt], 0, 0, 0);
        }
        __syncthreads();
    }
    // C/D fragment: row = quad*4 + reg, col = l16 (within each 16x16 tile)
    if (n0 < HDIM) {
        // ---- fused dots: this wave's head ----
        const int n = (n0 >> 6) + wn;
        float rh[4], bv[4];
#pragma unroll
        for (int nt = 0; nt < 4; nt++) {
            int col = n * 64 + nt * 16 + l16;
            rh[nt] = RH[col];
            bv[nt] = bias[col];
        }
#pragma unroll
        for (int mt = 0; mt < 4; mt++) {
#pragma unroll
            for (int r = 0; r < 4; r++) {
                float p = 0.f;
#pragma unroll
                for (int nt = 0; nt < 4; nt++)
                    p += fmaxf(acc[mt][nt][r] + bv[nt], 0.f) * rh[nt];
#pragma unroll
                for (int s = 8; s >= 1; s >>= 1) p += __shfl_xor(p, s, 64);
                if (l16 == 0) {
                    int row = m0 + wm * 64 + mt * 16 + quad * 4 + r;   // b*SEQ + l
                    int b = row >> 11, l = row & (SEQ - 1);
                    valid[((size_t)b * NH + n) * SEQ + l] = (p > 0.5f) ? 1 : 0;
                    if (fabsf(p - 0.5f) < DELTA) {
                        int idx = atomicAdd(&fcnt[n], 1);
                        if (idx < PERH_CAP) flist[n * PERH_CAP + idx] = row;
                    }
                }
            }
        }
    } else {
        // ---- V-half: bias + relu, store bf16 to CVh ----
        const int nv0 = n0 - HDIM;
#pragma unroll
        for (int mt = 0; mt < 4; mt++) {
            int gm = m0 + wm * 64 + mt * 16 + quad * 4;
#pragma unroll
            for (int nt = 0; nt < 4; nt++) {
                int gn = nv0 + wn * 64 + nt * 16 + l16;
                float bvv = bias[HDIM + gn];
#pragma unroll
                for (int r = 0; r < 4; r++)
                    CVh[(size_t)(gm + r) * HDIM + gn] = f2bf(fmaxf(acc[mt][nt][r] + bvv, 0.f));
            }
        }
    }
}

// ---------------- exact fp64 refinement v2: per-head, LDS-shared weights ----------------
// Tasks grouped by head (per-head lists from GEMM). 512-thread blocks pinned
// to head n = blockIdx.x>>5; 8 tasks/block (one per wave). Weight chunk
// K1w[kc..kc+128][n*64..+64] (32 KB f32) staged in LDS ONCE per task-group and
// consumed by all 8 waves -> weight traffic 1.6 GB -> ~200 MB (8x reuse).
// Same fp64 accumulation order/grouping as v1 (bit-identical decisions);
// w comes from an LDS copy of the same values. Dead waves (task >= cnt) skip
// compute but keep barriers (chunk-loop bounds are block-uniform).
__global__ __launch_bounds__(512) void refine_kernel(const float* __restrict__ hs,
                                                     const float* __restrict__ K1w,
                                                     const float* __restrict__ K1b,
                                                     const float* __restrict__ RH,
                                                     const int* __restrict__ fcnt,
                                                     const int* __restrict__ flist,
                                                     unsigned char* __restrict__ valid) {
    __shared__ float Wl[128 * 64];          // 32 KB k-major chunk [k][d]
    const int n = blockIdx.x >> 5;          // head 0..15
    const int g = blockIdx.x & 31;          // 32 blocks per head
    const int wave = threadIdx.x >> 6, d = threadIdx.x & 63;
    int cnt = fcnt[n];
    if (cnt > PERH_CAP) cnt = PERH_CAP;

    const int r0 = threadIdx.x >> 4;        // staging row 0..31
    const int c4 = (threadIdx.x & 15) * 4;  // staging col 0,4,..,60
    const float bn = K1b[n * 64 + d];
    const float rhn = RH[n * 64 + d];

    for (int base = g * 8; base < cnt; base += 32 * 8) {
        const int task = base + wave;
        const bool live = task < cnt;
        const int bl = live ? flist[n * PERH_CAP + task] : 0;   // b*SEQ + l
        const float* x = hs + (size_t)bl * HDIM;

        double acc0 = 0.0, acc1 = 0.0, acc2 = 0.0, acc3 = 0.0;
        for (int kc = 0; kc < KDIM; kc += 128) {
            // stage: 8192 floats, 512 threads x 4 float4; 16 threads cover a
            // 256B row segment (coalesced); LDS writes 2-way (free)
#pragma unroll
            for (int rr = 0; rr < 4; rr++) {
                const float4 v = *(const float4*)&K1w[(size_t)(kc + rr * 32 + r0) * 1024 + n * 64 + c4];
                *(float4*)&Wl[(rr * 32 + r0) * 64 + c4] = v;
            }
            __syncthreads();
            if (live) {
                for (int k = 0; k < 128; k += 32) {
                    float w[32];
#pragma unroll
                    for (int u = 0; u < 32; u++)
                        w[u] = Wl[(k + u) * 64 + d];        // 64 lanes consecutive: 2-way, free
                    float4 xv[8];
#pragma unroll
                    for (int u = 0; u < 8; u++)
                        xv[u] = *(const float4*)(x + kc + k + u * 4);
#pragma unroll
                    for (int u = 0; u < 8; u++) {
                        acc0 += (double)xv[u].x * (double)w[u * 4 + 0];
                        acc1 += (double)xv[u].y * (double)w[u * 4 + 1];
                        acc2 += (double)xv[u].z * (double)w[u * 4 + 2];
                        acc3 += (double)xv[u].w * (double)w[u * 4 + 3];
                    }
                }
            }
            __syncthreads();   // WAR: all reads done before next chunk stage
        }
        if (live) {
            double k1 = ((acc0 + acc1) + (acc2 + acc3)) + (double)bn;
            if (k1 < 0.0) k1 = 0.0;
            double contrib = k1 * (double)rhn;
#pragma unroll
            for (int s = 32; s >= 1; s >>= 1) contrib += __shfl_xor(contrib, s, 64);
            if (d == 0) {
                int b = bl >> 11, l = bl & (SEQ - 1);
                valid[((size_t)b * NH + n) * SEQ + l] = (contrib > 0.5) ? 1 : 0;
            }
        }
    }
}

// ---------------- nearest-valid scans ----------------
// one block (64 threads) per (b,n). Lane i owns positions [32i, 32i+32).
__global__ __launch_bounds__(64) void scan_kernel(const unsigned char* __restrict__ valid,
                                                  ushort4* __restrict__ maps) {
    int bn = blockIdx.x;                 // b*NH + n
    int b = bn >> 4, n = bn & (NH - 1);
    int lane = threadIdx.x;
    __shared__ unsigned int summ[64];

    const unsigned char* vp = valid + (size_t)bn * SEQ + lane * 32;
    uint4 c0 = *(const uint4*)vp;
    uint4 c1 = *(const uint4*)(vp + 16);
    unsigned int wds[8] = {c0.x, c0.y, c0.z, c0.w, c1.x, c1.y, c1.z, c1.w};
    unsigned int mask = 0;
#pragma unroll
    for (int i = 0; i < 8; i++) {
#pragma unroll
        for (int j = 0; j < 4; j++)
            mask |= (((wds[i] >> (8 * j)) & 0xffu) ? 1u : 0u) << (i * 4 + j);
    }

    // ---- forward ----
    int cnt = 0, va = 0, vb = 0;
#pragma unroll
    for (int tt = 0; tt < 32; tt++) {
        if (mask & (1u << tt)) { vb = va; va = lane * 32 + tt; cnt++; }
    }
    summ[lane] = (unsigned)((cnt > 2 ? 2 : cnt) | (va << 2) | (vb << 13));
    __syncthreads();
    int a = 0, bb_ = 0;
    for (int tt = 0; tt < lane; tt++) {
        unsigned s = summ[tt];
        int c = s & 3, sva = (s >> 2) & 2047, svb = (s >> 13) & 2047;
        if (c >= 2) { a = sva; bb_ = svb; }
        else if (c == 1) { bb_ = a; a = sva; }
    }
    unsigned int fres[32];
#pragma unroll
    for (int tt = 0; tt < 32; tt++) {
        if (mask & (1u << tt)) { bb_ = a; a = lane * 32 + tt; }
        fres[tt] = (unsigned)a | ((unsigned)bb_ << 16);
    }
    __syncthreads();

    // ---- backward (mirrored values) ----
    unsigned int maskb = mask;
    if (lane == 63) maskb &= ~(1u << 31);   // exclude j = L-1
    cnt = 0; va = 0; vb = 0;
#pragma unroll
    for (int tt = 31; tt >= 0; tt--) {
        if (maskb & (1u << tt)) { vb = va; va = (SEQ - 1) - (lane * 32 + tt); cnt++; }
    }
    summ[lane] = (unsigned)((cnt > 2 ? 2 : cnt) | (va << 2) | (vb << 13));
    __syncthreads();
    int a2 = SEQ - 1, b2 = SEQ - 1;
    for (int tt = 63; tt > lane; tt--) {
        unsigned s = summ[tt];
        int c = s & 3, sva = (s >> 2) & 2047, svb = (s >> 13) & 2047;
        if (c >= 2) { a2 = sva; b2 = svb; }
        else if (c == 1) { b2 = a2; a2 = sva; }
    }
#pragma unroll
    for (int tt = 31; tt >= 0; tt--) {
        int j = lane * 32 + tt;
        if (maskb & (1u << tt)) { b2 = a2; a2 = (SEQ - 1) - j; }
        unsigned f = fres[tt];
        maps[((size_t)b * SEQ + j) * NH + n] =
            make_ushort4((unsigned short)(f & 0xffffu), (unsigned short)(f >> 16),
                         (unsigned short)a2, (unsigned short)b2);
    }
}

// ---------------- gather + weighted sum (CVh bf16 [M][1024]) ----------------
__global__ __launch_bounds__(256) void gather_kernel(const unsigned short* __restrict__ CVh,
                                                     const ushort4* __restrict__ maps,
                                                     const float* __restrict__ bw,
                                                     float* __restrict__ out) {
    int bl = blockIdx.x;
    int t = threadIdx.x, n = t >> 4, q = t & 15;
    int b = bl >> 11;
    ushort4 m = maps[(size_t)bl * NH + n];
    const float4 w = *(const float4*)&bw[n * 4];
    size_t colbase = (size_t)(n * 64 + q * 4);
    size_t rowb = (size_t)b * SEQ;
    const ushort4 u0 = *(const ushort4*)&CVh[(rowb + m.x) * HDIM + colbase];
    const ushort4 u1 = *(const ushort4*)&CVh[(rowb + m.y) * HDIM + colbase];
    const ushort4 u2 = *(const ushort4*)&CVh[(rowb + m.z) * HDIM + colbase];
    const ushort4 u3 = *(const ushort4*)&CVh[(rowb + m.w) * HDIM + colbase];
    float4 o;
    o.x = w.x * bf2f(u0.x) + w.y * bf2f(u1.x) + w.z * bf2f(u2.x) + w.w * bf2f(u3.x);
    o.y = w.x * bf2f(u0.y) + w.y * bf2f(u1.y) + w.z * bf2f(u2.y) + w.w * bf2f(u3.y);
    o.z = w.x * bf2f(u0.z) + w.y * bf2f(u1.z) + w.z * bf2f(u2.z) + w.w * bf2f(u3.z);
    o.w = w.x * bf2f(u0.w) + w.y * bf2f(u1.w) + w.z * bf2f(u2.w) + w.w * bf2f(u3.w);
    *(float4*)&out[(size_t)bl * (NH * HD) + n * 64 + q * 4] = o;
}

// ---------------- launch ----------------
extern "C" void kernel_launch(void* const* d_in, const int* in_sizes, int n_in,
                              void* d_out, int out_size, void* d_ws, size_t ws_size,
                              hipStream_t stream) {
    (void)in_sizes; (void)n_in; (void)out_size; (void)ws_size;
    const float* hs  = (const float*)d_in[0];
    const float* K1w = (const float*)d_in[1];
    const float* K1b = (const float*)d_in[2];
    const float* V1w = (const float*)d_in[3];
    const float* V1b = (const float*)d_in[4];
    const float* bw  = (const float*)d_in[5];
    const float* RH  = (const float*)d_in[6];
    float* out = (float*)d_out;
    char* ws = (char*)d_ws;

    unsigned short* Abf  = (unsigned short*)(ws + OFF_A);
    unsigned short* Btbf = (unsigned short*)(ws + OFF_BT);
    int* fcnt = (int*)(ws + OFF_FCNT);
    int* flist = (int*)(ws + OFF_FLIST);
    float* bias  = (float*)(ws + OFF_BIAS);
    unsigned short* CVh = (unsigned short*)(ws + OFF_CVH);
    unsigned char* valid = (unsigned char*)(ws + OFF_VALID);
    ushort4* maps = (ushort4*)(ws + OFF_MAPS);

    prep_kernel<<<10248, 256, 0, stream>>>((const float4*)hs, Abf,
                                           K1w, V1w, Btbf, K1b, V1b, bias, fcnt);
    gemm_kernel<<<dim3(N_COLS / 128, M_ROWS / 128), 256, 0, stream>>>(
        Abf, Btbf, bias, RH, CVh, valid, fcnt, flist);
    refine_kernel<<<NH * 32, 512, 0, stream>>>(
        hs, K1w, K1b, RH, fcnt, flist, valid);
    scan_kernel<<<BS * NH, 64, 0, stream>>>(valid, maps);
    gather_kernel<<<BS * SEQ, 256, 0, stream>>>(CVh, maps, bw, out);
}

// Round 8
// 343.089 us; speedup vs baseline: 1.1683x; 1.0210x over previous
//
#include <hip/hip_runtime.h>
#include <hip/hip_bf16.h>
#include <cstdint>

// ---------------- problem dims ----------------
#define BS 8
#define SEQ 2048
#define HDIM 1024
#define NH 16
#define HD 64
#define M_ROWS (BS * SEQ)   // 16384
#define N_COLS (2 * HDIM)   // 2048 GEMM cols: 0..1023 = K1 (dots only), 1024..2047 = V1
#define KDIM HDIM           // 1024

#define DELTA 0.025f
#define PERH_CAP 2048            // per-head flagged-task list; expected ~390/head

// ---------------- workspace layout (bytes) ----------------
#define OFF_A      ((size_t)0)           // bf16 A [M,K]             33,554,432
#define OFF_BT     ((size_t)33554432)    // bf16 Bt [N,K]             4,194,304
#define OFF_FCNT   ((size_t)37748736)    // int[16]
#define OFF_FLIST  ((size_t)37748800)    // int[16][2048]               131,072
#define OFF_BIAS   ((size_t)37879872)    // f32 [2048]
#define OFF_CVH    ((size_t)41943040)    // bf16 CV [M,1024]          33,554,432
#define OFF_VALID  ((size_t)75497472)    // u8 [BS][NH][SEQ]             262,144
#define OFF_MAPS   ((size_t)75759616)    // ushort4 [BS][NH][SEQ]      2,097,152
// total ~78 MB

typedef __attribute__((ext_vector_type(8))) __bf16 bf16x8;
typedef __attribute__((ext_vector_type(4))) float f32x4;
typedef __attribute__((ext_vector_type(8))) unsigned short ushort8;

// float -> bf16 bits, round-to-nearest-even (inputs are finite)
__device__ __forceinline__ unsigned short f2bf(float f) {
    unsigned int x = __builtin_bit_cast(unsigned int, f);
    unsigned int r = x + 0x7fffu + ((x >> 16) & 1u);
    return (unsigned short)(r >> 16);
}
__device__ __forceinline__ float bf2f(unsigned short u) {
    return __builtin_bit_cast(float, (unsigned int)u << 16);
}

// async 16B global -> LDS (dest = wave-uniform LDS base + lane*16)
__device__ __forceinline__ void g2l16(const void* gp, void* lp) {
    __builtin_amdgcn_global_load_lds(
        (__attribute__((address_space(1))) void*)(void*)gp,
        (__attribute__((address_space(3))) void*)lp, 16, 0, 0);
}

// ---------------- fused prep: hs->bf16 | W transpose->bf16 | bias+fcnt ----------------
__global__ __launch_bounds__(256) void prep_kernel(const float4* __restrict__ hs4,
                                                   unsigned short* __restrict__ Abf,
                                                   const float* __restrict__ K1w,
                                                   const float* __restrict__ V1w,
                                                   unsigned short* __restrict__ Bt,
                                                   const float* __restrict__ K1b,
                                                   const float* __restrict__ V1b,
                                                   float* __restrict__ bias,
                                                   int* __restrict__ fcnt) {
    __shared__ float tile[32][33];
    const int blk = blockIdx.x;
    const int t = threadIdx.x;
    if (blk < 8192) {
        int i = blk * 256 + t;            // 2,097,152 uint4 stores
        float4 v0 = hs4[i * 2];
        float4 v1 = hs4[i * 2 + 1];
        uint4 o;
        o.x = (unsigned)f2bf(v0.x) | ((unsigned)f2bf(v0.y) << 16);
        o.y = (unsigned)f2bf(v0.z) | ((unsigned)f2bf(v0.w) << 16);
        o.z = (unsigned)f2bf(v1.x) | ((unsigned)f2bf(v1.y) << 16);
        o.w = (unsigned)f2bf(v1.z) | ((unsigned)f2bf(v1.w) << 16);
        ((uint4*)Abf)[i] = o;
    } else if (blk < 10240) {
        int lb = blk - 8192;              // 0..2047 = tn + 32*tk + 1024*z
        int z = lb >> 10;
        int tk = (lb >> 5) & 31;
        int tn = lb & 31;
        const float* W = z ? V1w : K1w;
        int r = t >> 3;                   // 0..31
        int c4 = (t & 7) * 4;             // 0,4,..,28
        const float4 v = *(const float4*)&W[(size_t)(tk * 32 + r) * 1024 + tn * 32 + c4];
        tile[r][c4 + 0] = v.x; tile[r][c4 + 1] = v.y;
        tile[r][c4 + 2] = v.z; tile[r][c4 + 3] = v.w;
        __syncthreads();
        int n = tn * 32 + r;
        int k = tk * 32 + c4;
        ushort4 o;
        o.x = f2bf(tile[c4 + 0][r]); o.y = f2bf(tile[c4 + 1][r]);
        o.z = f2bf(tile[c4 + 2][r]); o.w = f2bf(tile[c4 + 3][r]);
        *(ushort4*)&Bt[((size_t)z * 1024 + n) * 1024 + k] = o;
    } else {
        int i = (blk - 10240) * 256 + t;  // 0..2047
        bias[i] = (i < 1024) ? K1b[i] : V1b[i - 1024];
        if (i < 16) fcnt[i] = 0;
    }
}

// ---------------- GEMM + fused dots (R0 structure + T1 XCD swizzle) ----------------
// A [M,K] bf16, Bt [N,K] bf16. 128x128 tile, BK=64, 4 waves 2x2, 16 K-iters.
// XOR-swizzled staging (verified, 0 bank conflicts). T1 bijective XCD remap
// (confirmed: FETCH 139->82 MB; time-neutral but kept for the traffic win).
// n0 <  1024: fused dots epilogue -> valid + PER-HEAD flag lists.
// n0 >= 1024: relu(acc+bias) -> CVh (bf16) [M][1024].
__global__ __launch_bounds__(256) void gemm_kernel(const unsigned short* __restrict__ Abf,
                                                   const unsigned short* __restrict__ Btbf,
                                                   const float* __restrict__ bias,
                                                   const float* __restrict__ RH,
                                                   unsigned short* __restrict__ CVh,
                                                   unsigned char* __restrict__ valid,
                                                   int* __restrict__ fcnt,
                                                   int* __restrict__ flist) {
    constexpr int K = KDIM, BK = 64;
    __shared__ unsigned short As[128 * BK];   // [row][64] with XOR-swizzled groups
    __shared__ unsigned short Bs[128 * BK];
    const int t = threadIdx.x;
    const int wave = t >> 6, lane = t & 63;
    const int wm = wave >> 1, wn = wave & 1;
    const int l16 = lane & 15, quad = lane >> 4;
    const int sw = l16 & 7;                  // read-side XOR key (r&7 == l16&7)

    // T1: bijective XCD-contiguous remap of the 16x128 tile grid
    const int wgid = blockIdx.y * 16 + blockIdx.x;      // 0..2047, x-fastest
    const int swz = (wgid & 7) * 256 + (wgid >> 3);
    const int m0 = (swz >> 4) * 128, n0 = (swz & 15) * 128;

    f32x4 zero4 = {0.f, 0.f, 0.f, 0.f};
    f32x4 acc[4][4];
#pragma unroll
    for (int i = 0; i < 4; i++)
#pragma unroll
        for (int j = 0; j < 4; j++) acc[i][j] = zero4;

    // staging roles: rr = row 0..31 (per issue), g = 16B-group 0..7
    const int rr = t >> 3;
    const int gsw = (t ^ (t >> 3)) & 7;      // g ^ (row&7); row&7 invariant across issues
    const unsigned short* gA = Abf + (size_t)(m0 + rr) * K + gsw * 8;
    const unsigned short* gB = Btbf + (size_t)(n0 + rr) * K + gsw * 8;
    char* lAs = (char*)As + (size_t)wave * 1024;
    char* lBs = (char*)Bs + (size_t)wave * 1024;

    for (int k0 = 0; k0 < K; k0 += BK) {
#pragma unroll
        for (int i = 0; i < 4; i++)
            g2l16(gA + (size_t)i * 32 * K + k0, lAs + i * 4096);
#pragma unroll
        for (int i = 0; i < 4; i++)
            g2l16(gB + (size_t)i * 32 * K + k0, lBs + i * 4096);
        __syncthreads();   // drains global_load_lds (vmcnt) + barrier
#pragma unroll
        for (int h = 0; h < 2; h++) {
            bf16x8 af[4], bfr[4];
            const int hq = h * 4 + quad;
#pragma unroll
            for (int mt = 0; mt < 4; mt++)
                af[mt] = *(const bf16x8*)&As[(wm * 64 + mt * 16 + l16) * BK + (hq ^ sw) * 8];
#pragma unroll
            for (int nt = 0; nt < 4; nt++)
                bfr[nt] = *(const bf16x8*)&Bs[(wn * 64 + nt * 16 + l16) * BK + (hq ^ sw) * 8];
#pragma unroll
            for (int mt = 0; mt < 4; mt++)
#pragma unroll
                for (int nt = 0; nt < 4; nt++)
                    acc[mt][nt] = __builtin_amdgcn_mfma_f32_16x16x32_bf16(af[mt], bfr[nt], acc[mt][nt], 0, 0, 0);
        }
        __syncthreads();
    }
    // C/D fragment: row = quad*4 + reg, col = l16 (within each 16x16 tile)
    if (n0 < HDIM) {
        // ---- fused dots: this wave's head ----
        const int n = (n0 >> 6) + wn;
        float rh[4], bv[4];
#pragma unroll
        for (int nt = 0; nt < 4; nt++) {
            int col = n * 64 + nt * 16 + l16;
            rh[nt] = RH[col];
            bv[nt] = bias[col];
        }
#pragma unroll
        for (int mt = 0; mt < 4; mt++) {
#pragma unroll
            for (int r = 0; r < 4; r++) {
                float p = 0.f;
#pragma unroll
                for (int nt = 0; nt < 4; nt++)
                    p += fmaxf(acc[mt][nt][r] + bv[nt], 0.f) * rh[nt];
#pragma unroll
                for (int s = 8; s >= 1; s >>= 1) p += __shfl_xor(p, s, 64);
                if (l16 == 0) {
                    int row = m0 + wm * 64 + mt * 16 + quad * 4 + r;   // b*SEQ + l
                    int b = row >> 11, l = row & (SEQ - 1);
                    valid[((size_t)b * NH + n) * SEQ + l] = (p > 0.5f) ? 1 : 0;
                    if (fabsf(p - 0.5f) < DELTA) {
                        int idx = atomicAdd(&fcnt[n], 1);
                        if (idx < PERH_CAP) flist[n * PERH_CAP + idx] = row;
                    }
                }
            }
        }
    } else {
        // ---- V-half: bias + relu, store bf16 to CVh ----
        const int nv0 = n0 - HDIM;
#pragma unroll
        for (int mt = 0; mt < 4; mt++) {
            int gm = m0 + wm * 64 + mt * 16 + quad * 4;
#pragma unroll
            for (int nt = 0; nt < 4; nt++) {
                int gn = nv0 + wn * 64 + nt * 16 + l16;
                float bvv = bias[HDIM + gn];
#pragma unroll
                for (int r = 0; r < 4; r++)
                    CVh[(size_t)(gm + r) * HDIM + gn] = f2bf(fmaxf(acc[mt][nt][r] + bvv, 0.f));
            }
        }
    }
}

// ---------------- exact fp64 refinement v2: per-head, LDS-shared weights ----------------
// (unchanged from R7 — measured -19 us vs v1)
__global__ __launch_bounds__(512) void refine_kernel(const float* __restrict__ hs,
                                                     const float* __restrict__ K1w,
                                                     const float* __restrict__ K1b,
                                                     const float* __restrict__ RH,
                                                     const int* __restrict__ fcnt,
                                                     const int* __restrict__ flist,
                                                     unsigned char* __restrict__ valid) {
    __shared__ float Wl[128 * 64];          // 32 KB k-major chunk [k][d]
    const int n = blockIdx.x >> 5;          // head 0..15
    const int g = blockIdx.x & 31;          // 32 blocks per head
    const int wave = threadIdx.x >> 6, d = threadIdx.x & 63;
    int cnt = fcnt[n];
    if (cnt > PERH_CAP) cnt = PERH_CAP;

    const int r0 = threadIdx.x >> 4;        // staging row 0..31
    const int c4 = (threadIdx.x & 15) * 4;  // staging col 0,4,..,60
    const float bn = K1b[n * 64 + d];
    const float rhn = RH[n * 64 + d];

    for (int base = g * 8; base < cnt; base += 32 * 8) {
        const int task = base + wave;
        const bool live = task < cnt;
        const int bl = live ? flist[n * PERH_CAP + task] : 0;   // b*SEQ + l
        const float* x = hs + (size_t)bl * HDIM;

        double acc0 = 0.0, acc1 = 0.0, acc2 = 0.0, acc3 = 0.0;
        for (int kc = 0; kc < KDIM; kc += 128) {
#pragma unroll
            for (int rr = 0; rr < 4; rr++) {
                const float4 v = *(const float4*)&K1w[(size_t)(kc + rr * 32 + r0) * 1024 + n * 64 + c4];
                *(float4*)&Wl[(rr * 32 + r0) * 64 + c4] = v;
            }
            __syncthreads();
            if (live) {
                for (int k = 0; k < 128; k += 32) {
                    float w[32];
#pragma unroll
                    for (int u = 0; u < 32; u++)
                        w[u] = Wl[(k + u) * 64 + d];        // 64 lanes consecutive: 2-way, free
                    float4 xv[8];
#pragma unroll
                    for (int u = 0; u < 8; u++)
                        xv[u] = *(const float4*)(x + kc + k + u * 4);
#pragma unroll
                    for (int u = 0; u < 8; u++) {
                        acc0 += (double)xv[u].x * (double)w[u * 4 + 0];
                        acc1 += (double)xv[u].y * (double)w[u * 4 + 1];
                        acc2 += (double)xv[u].z * (double)w[u * 4 + 2];
                        acc3 += (double)xv[u].w * (double)w[u * 4 + 3];
                    }
                }
            }
            __syncthreads();   // WAR: all reads done before next chunk stage
        }
        if (live) {
            double k1 = ((acc0 + acc1) + (acc2 + acc3)) + (double)bn;
            if (k1 < 0.0) k1 = 0.0;
            double contrib = k1 * (double)rhn;
#pragma unroll
            for (int s = 32; s >= 1; s >>= 1) contrib += __shfl_xor(contrib, s, 64);
            if (d == 0) {
                int b = bl >> 11, l = bl & (SEQ - 1);
                valid[((size_t)b * NH + n) * SEQ + l] = (contrib > 0.5) ? 1 : 0;
            }
        }
    }
}

// ---------------- nearest-valid scans ----------------
// one block (64 threads) per (b,n). Lane i owns positions [32i, 32i+32).
// maps layout v2: [B][NH][SEQ] -> each lane writes 32 CONSECUTIVE ushort4
// (256 B contiguous; wave covers 16 KB streaming) instead of 128-B-strided
// single-line 8-B stores. Gather reads maps[(b*NH+n)*SEQ+l] (L2-cached).
__global__ __launch_bounds__(64) void scan_kernel(const unsigned char* __restrict__ valid,
                                                  ushort4* __restrict__ maps) {
    int bn = blockIdx.x;                 // b*NH + n
    int lane = threadIdx.x;
    __shared__ unsigned int summ[64];

    const unsigned char* vp = valid + (size_t)bn * SEQ + lane * 32;
    uint4 c0 = *(const uint4*)vp;
    uint4 c1 = *(const uint4*)(vp + 16);
    unsigned int wds[8] = {c0.x, c0.y, c0.z, c0.w, c1.x, c1.y, c1.z, c1.w};
    unsigned int mask = 0;
#pragma unroll
    for (int i = 0; i < 8; i++) {
#pragma unroll
        for (int j = 0; j < 4; j++)
            mask |= (((wds[i] >> (8 * j)) & 0xffu) ? 1u : 0u) << (i * 4 + j);
    }

    // ---- forward ----
    int cnt = 0, va = 0, vb = 0;
#pragma unroll
    for (int tt = 0; tt < 32; tt++) {
        if (mask & (1u << tt)) { vb = va; va = lane * 32 + tt; cnt++; }
    }
    summ[lane] = (unsigned)((cnt > 2 ? 2 : cnt) | (va << 2) | (vb << 13));
    __syncthreads();
    int a = 0, bb_ = 0;
    for (int tt = 0; tt < lane; tt++) {
        unsigned s = summ[tt];
        int c = s & 3, sva = (s >> 2) & 2047, svb = (s >> 13) & 2047;
        if (c >= 2) { a = sva; bb_ = svb; }
        else if (c == 1) { bb_ = a; a = sva; }
    }
    unsigned int fres[32];
#pragma unroll
    for (int tt = 0; tt < 32; tt++) {
        if (mask & (1u << tt)) { bb_ = a; a = lane * 32 + tt; }
        fres[tt] = (unsigned)a | ((unsigned)bb_ << 16);
    }
    __syncthreads();

    // ---- backward (mirrored values) ----
    unsigned int maskb = mask;
    if (lane == 63) maskb &= ~(1u << 31);   // exclude j = L-1
    cnt = 0; va = 0; vb = 0;
#pragma unroll
    for (int tt = 31; tt >= 0; tt--) {
        if (maskb & (1u << tt)) { vb = va; va = (SEQ - 1) - (lane * 32 + tt); cnt++; }
    }
    summ[lane] = (unsigned)((cnt > 2 ? 2 : cnt) | (va << 2) | (vb << 13));
    __syncthreads();
    int a2 = SEQ - 1, b2 = SEQ - 1;
    for (int tt = 63; tt > lane; tt--) {
        unsigned s = summ[tt];
        int c = s & 3, sva = (s >> 2) & 2047, svb = (s >> 13) & 2047;
        if (c >= 2) { a2 = sva; b2 = svb; }
        else if (c == 1) { b2 = a2; a2 = sva; }
    }
#pragma unroll
    for (int tt = 31; tt >= 0; tt--) {
        int j = lane * 32 + tt;
        if (maskb & (1u << tt)) { b2 = a2; a2 = (SEQ - 1) - j; }
        unsigned f = fres[tt];
        maps[(size_t)bn * SEQ + j] =
            make_ushort4((unsigned short)(f & 0xffffu), (unsigned short)(f >> 16),
                         (unsigned short)a2, (unsigned short)b2);
    }
}

// ---------------- gather + weighted sum (CVh bf16 [M][1024]) ----------------
// v2: 8 threads/head x 8 elems (ushort8 16-B loads -> half the scattered
// load instructions), 2 rows per 256-thread block. maps in [B][NH][SEQ].
// Per-element arithmetic expression identical to v1 -> bit-identical output.
__global__ __launch_bounds__(256) void gather_kernel(const unsigned short* __restrict__ CVh,
                                                     const ushort4* __restrict__ maps,
                                                     const float* __restrict__ bw,
                                                     float* __restrict__ out) {
    const int t = threadIdx.x;
    const int sub = t >> 7, tt = t & 127;
    const int n = tt >> 3, q8 = tt & 7;
    const int bl = blockIdx.x * 2 + sub;
    const int b = bl >> 11, l = bl & (SEQ - 1);
    const ushort4 m = maps[((size_t)(b * NH + n)) * SEQ + l];
    const float4 w = *(const float4*)&bw[n * 4];
    const size_t colbase = (size_t)(n * 64 + q8 * 8);
    const size_t rowb = (size_t)b * SEQ;
    const ushort8 u0 = *(const ushort8*)&CVh[(rowb + m.x) * HDIM + colbase];
    const ushort8 u1 = *(const ushort8*)&CVh[(rowb + m.y) * HDIM + colbase];
    const ushort8 u2 = *(const ushort8*)&CVh[(rowb + m.z) * HDIM + colbase];
    const ushort8 u3 = *(const ushort8*)&CVh[(rowb + m.w) * HDIM + colbase];
    float o[8];
#pragma unroll
    for (int e = 0; e < 8; e++)
        o[e] = w.x * bf2f(u0[e]) + w.y * bf2f(u1[e]) + w.z * bf2f(u2[e]) + w.w * bf2f(u3[e]);
    float* op = &out[(size_t)bl * (NH * HD) + n * 64 + q8 * 8];
    *(float4*)op       = make_float4(o[0], o[1], o[2], o[3]);
    *(float4*)(op + 4) = make_float4(o[4], o[5], o[6], o[7]);
}

// ---------------- launch ----------------
extern "C" void kernel_launch(void* const* d_in, const int* in_sizes, int n_in,
                              void* d_out, int out_size, void* d_ws, size_t ws_size,
                              hipStream_t stream) {
    (void)in_sizes; (void)n_in; (void)out_size; (void)ws_size;
    const float* hs  = (const float*)d_in[0];
    const float* K1w = (const float*)d_in[1];
    const float* K1b = (const float*)d_in[2];
    const float* V1w = (const float*)d_in[3];
    const float* V1b = (const float*)d_in[4];
    const float* bw  = (const float*)d_in[5];
    const float* RH  = (const float*)d_in[6];
    float* out = (float*)d_out;
    char* ws = (char*)d_ws;

    unsigned short* Abf  = (unsigned short*)(ws + OFF_A);
    unsigned short* Btbf = (unsigned short*)(ws + OFF_BT);
    int* fcnt = (int*)(ws + OFF_FCNT);
    int* flist = (int*)(ws + OFF_FLIST);
    float* bias  = (float*)(ws + OFF_BIAS);
    unsigned short* CVh = (unsigned short*)(ws + OFF_CVH);
    unsigned char* valid = (unsigned char*)(ws + OFF_VALID);
    ushort4* maps = (ushort4*)(ws + OFF_MAPS);

    prep_kernel<<<10248, 256, 0, stream>>>((const float4*)hs, Abf,
                                           K1w, V1w, Btbf, K1b, V1b, bias, fcnt);
    gemm_kernel<<<dim3(N_COLS / 128, M_ROWS / 128), 256, 0, stream>>>(
        Abf, Btbf, bias, RH, CVh, valid, fcnt, flist);
    refine_kernel<<<NH * 32, 512, 0, stream>>>(
        hs, K1w, K1b, RH, fcnt, flist, valid);
    scan_kernel<<<BS * NH, 64, 0, stream>>>(valid, maps);
    gather_kernel<<<(BS * SEQ) / 2, 256, 0, stream>>>(CVh, maps, bw, out);
}